// Round 4
// baseline (161.052 us; speedup 1.0000x reference)
//
#include <hip/hip_runtime.h>

#define B_DIMC   128
#define S_DIMC   4096
#define N_TOK    (B_DIMC * S_DIMC)
#define CHUNK    256                 // tokens per msc block == scan chunk
#define N_CHUNK  (N_TOK / CHUNK)     // 2048
#define CPB      (S_DIMC / CHUNK)    // 16 chunks per batch

typedef __attribute__((ext_vector_type(8))) short  short8;   // 8 bf16 (4 VGPR) MFMA A/B frag
typedef __attribute__((ext_vector_type(4))) float  floatx4;  // MFMA C/D frag
typedef __attribute__((ext_vector_type(4))) int    intx4;

__device__ float g_chunksums[N_CHUNK];

__device__ __forceinline__ unsigned short f2bf(float f) {
    unsigned u = __builtin_bit_cast(unsigned, f);
    u = (u + 0x7FFFu + ((u >> 16) & 1u)) >> 16;   // round-to-nearest-even
    return (unsigned short)u;
}
__device__ __forceinline__ int packbf(float a, float b) {
    return (int)f2bf(a) | ((int)f2bf(b) << 16);
}
// tanh(x) = 1 - 2/(exp2(2*log2e*x)+1); med3 clamp keeps exp2 in range
__device__ __forceinline__ float fast_tanh(float x) {
    float e = __builtin_amdgcn_exp2f(2.885390082f * __builtin_amdgcn_fmed3f(x, -9.0f, 9.0f));
    return fmaf(-2.0f, __builtin_amdgcn_rcpf(e + 1.0f), 1.0f);
}
// tanh(a)*tanh(b) = (ea-1)(eb-1)/((ea+1)(eb+1)) with e* = exp2(2log2e * x)
//                 = (t-u)/(t+u),  t = ea*eb+1, u = ea+eb   (3 trans vs 4)
__device__ __forceinline__ float gate2(float a, float b) {
    const float c = 2.885390082f;
    float ea = __builtin_amdgcn_exp2f(c * __builtin_amdgcn_fmed3f(a, -9.0f, 9.0f));
    float eb = __builtin_amdgcn_exp2f(c * __builtin_amdgcn_fmed3f(b, -9.0f, 9.0f));
    float t  = fmaf(ea, eb, 1.0f);
    float u  = ea + eb;
    return (t - u) * __builtin_amdgcn_rcpf(t + u);
}

// -------- K1: per-chunk sum of delta_x[..., 2] --------
__global__ __launch_bounds__(256) void chunksum_kernel(const float* __restrict__ dx) {
    const int t    = blockIdx.x * CHUNK + threadIdx.x;
    const int lane = threadIdx.x & 63;
    const int wid  = threadIdx.x >> 6;
    __shared__ float wsum[4];
    float x = dx[(size_t)t * 6 + 2];
    #pragma unroll
    for (int off = 32; off >= 1; off >>= 1) x += __shfl_down(x, off, 64);
    if (lane == 0) wsum[wid] = x;
    __syncthreads();
    if (threadIdx.x == 0)
        g_chunksums[blockIdx.x] = wsum[0] + wsum[1] + wsum[2] + wsum[3];
}

__device__ __forceinline__ short8 zero8() {
    short8 z = { 0, 0, 0, 0, 0, 0, 0, 0 };
    return z;
}
// layer-0 B frag (W is 9x32): valid k in {0..8}\{5}; k>=9 rows don't exist -> no OOB loads
__device__ __forceinline__ short8 load_bfrag_l0(const float* __restrict__ W, int col, int quad) {
    short8 f = zero8();
    if (quad == 0) {
        float v[8];
        #pragma unroll
        for (int j = 0; j < 8; ++j) v[j] = (j == 5) ? 0.0f : W[j * 32 + col];
        #pragma unroll
        for (int jp = 0; jp < 4; ++jp) ((int*)&f)[jp] = packbf(v[2*jp], v[2*jp+1]);
    } else if (quad == 1) {
        ((int*)&f)[0] = packbf(W[8 * 32 + col], 0.0f);
    }
    return f;
}
// layer-1 B frag (W is 32x32, full K)
__device__ __forceinline__ short8 load_bfrag(const float* __restrict__ W, int col, int quad) {
    short8 f;
    #pragma unroll
    for (int jp = 0; jp < 4; ++jp) {
        const int k = quad * 8 + jp * 2;
        ((int*)&f)[jp] = packbf(W[k * 32 + col], W[(k + 1) * 32 + col]);
    }
    return f;
}
// head B frag: cols = [alpha, beta, gamma, c0..c4, 0 x8]
__device__ __forceinline__ short8 load_bfrag_head(int n, int quad,
        const float* __restrict__ Wal, const float* __restrict__ Wbe,
        const float* __restrict__ Wga, const float* __restrict__ Wc) {
    short8 f = zero8();
    if (n < 8) {
        #pragma unroll
        for (int jp = 0; jp < 4; ++jp) {
            const int k0 = quad * 8 + jp * 2, k1 = k0 + 1;
            float v0, v1;
            if      (n == 0) { v0 = Wal[k0]; v1 = Wal[k1]; }
            else if (n == 1) { v0 = Wbe[k0]; v1 = Wbe[k1]; }
            else if (n == 2) { v0 = Wga[k0]; v1 = Wga[k1]; }
            else             { v0 = Wc[k0 * 5 + (n - 3)]; v1 = Wc[k1 * 5 + (n - 3)]; }
            ((int*)&f)[jp] = packbf(v0, v1);
        }
    }
    return f;
}

// -------- K2: MFMA token-parallel MLP with fused scan --------
__global__ __launch_bounds__(256, 7) void msc_kernel(
    const float* __restrict__ h_prev, const float* __restrict__ dx,
    const float* __restrict__ Wa0, const float* __restrict__ ba0,
    const float* __restrict__ Wb0, const float* __restrict__ bb0,
    const float* __restrict__ Wa1, const float* __restrict__ ba1,
    const float* __restrict__ Wb1, const float* __restrict__ bb1,
    const float* __restrict__ W_alpha, const float* __restrict__ b_alpha,
    const float* __restrict__ W_beta,  const float* __restrict__ b_beta,
    const float* __restrict__ W_gamma, const float* __restrict__ b_gamma,
    const float* __restrict__ W_c,     const float* __restrict__ b_c,
    const float* __restrict__ W_out,
    float* __restrict__ out)
{
    // LDS: per-wave A zones only (B operands live in registers, loaded from global).
    // Rows padded to 40 bf16 (80 B): keeps ds_write_b16 gate stores ~2-way (free).
    __shared__ __align__(16) short sA[4][64][40];   // per-wave activations [tok][k]
    __shared__ __align__(16) float sTemps[4][64];   // per-wave temp_seq (fp32!)
    __shared__ float sWsum[4];

    const int tid  = threadIdx.x;
    const int w    = tid >> 6;
    const int lane = tid & 63;
    const int n    = lane & 15;
    const int quad = lane >> 4;
    const int t    = blockIdx.x * CHUNK + tid;

    // ---- per-token global loads ----
    const float* hp = h_prev + (size_t)t * 5;
    const float* d  = dx     + (size_t)t * 6;
    const float hp0 = hp[0], hp1 = hp[1], hp2 = hp[2], hp3 = hp[3], hp4 = hp[4];
    const float df0 = d[0], df1 = d[1], df2 = d[2];

    // ---- chunk offset: 1 load/lane + butterfly reduce (replaces 15 loads/thread) ----
    const int batch = blockIdx.x / CPB;
    const int cib   = blockIdx.x % CPB;
    float cs = (lane < cib) ? g_chunksums[batch * CPB + lane] : 0.0f;
    #pragma unroll
    for (int m = 1; m < 64; m <<= 1) cs += __shfl_xor(cs, m, 64);
    const float coff = dx[(size_t)batch * S_DIMC * 6 + 5] + cs;   // init_temp + prefix

    // ---- per-lane fp32 epilogue weights (L1/L2-cached) ----
    float w5a[2], w5b[2], bA0[2], bB0[2], bA1[2], bB1[2];
    #pragma unroll
    for (int nt = 0; nt < 2; ++nt) {
        const int col = nt * 16 + n;
        w5a[nt] = Wa0[5 * 32 + col];  w5b[nt] = Wb0[5 * 32 + col];
        bA0[nt] = ba0[col];           bB0[nt] = bb0[col];
        bA1[nt] = ba1[col];           bB1[nt] = bb1[col];
    }

    // ---- wave-level inclusive scan of df2 ----
    float x = df2;
    #pragma unroll
    for (int off = 1; off < 64; off <<= 1) {
        float y = __shfl_up(x, off, 64);
        if (lane >= off) x += y;
    }
    if (lane == 63) sWsum[w] = x;

    // ---- write layer0 A row: [h(5), 0(temp folded to C), dir(3), 0...] ----
    const float nrm = fmaxf(sqrtf(df0*df0 + df1*df1 + df2*df2), 1e-7f);
    const float inv = __builtin_amdgcn_rcpf(nrm);
    {
        int* arow = (int*)&sA[w][lane][0];
        intx4 v0 = { packbf(hp0, hp1), packbf(hp2, hp3),
                     packbf(hp4, 0.0f), packbf(df0*inv, df1*inv) };
        intx4 v1 = { packbf(df2*inv, 0.0f), 0, 0, 0 };
        intx4 z  = { 0, 0, 0, 0 };
        *(intx4*)&arow[0]  = v0;
        *(intx4*)&arow[4]  = v1;
        *(intx4*)&arow[8]  = z;
        *(intx4*)&arow[12] = z;
    }

    // ---- B fragments direct from global (per-lane, reused across all 4 M-tiles) ----
    short8 Ba0f[2], Bb0f[2], Ba1f[2], Bb1f[2], Bhf;
    #pragma unroll
    for (int nt = 0; nt < 2; ++nt) {
        const int col = nt * 16 + n;
        Ba0f[nt] = load_bfrag_l0(Wa0, col, quad);
        Bb0f[nt] = load_bfrag_l0(Wb0, col, quad);
        Ba1f[nt] = load_bfrag(Wa1, col, quad);
        Bb1f[nt] = load_bfrag(Wb1, col, quad);
    }
    Bhf = load_bfrag_head(n, quad, W_alpha, W_beta, W_gamma, W_c);
    const float hbias = (n == 0) ? b_alpha[0] : (n == 1) ? b_beta[0]
                      : (n == 2) ? b_gamma[0] : (n < 8) ? b_c[n - 3] : 0.0f;

    __syncthreads();   // sWsum cross-wave visibility (also covers A-row writes)

    // ---- temp_seq (fp32, stays out of bf16 path) ----
    float pre = coff;
    if (w > 0) pre += sWsum[0];
    if (w > 1) pre += sWsum[1];
    if (w > 2) pre += sWsum[2];
    const float temp_t = pre + x;
    sTemps[w][lane] = temp_t;

    // ---- layer 0: C-init = bias + temp*W[5][n] (fp32), MFMA, gate, write G1 ----
    #pragma unroll
    for (int mt = 0; mt < 4; ++mt) {
        const short8  Af = *(const short8*)&sA[w][mt * 16 + n][quad * 8];
        const floatx4 tv = *(const floatx4*)&sTemps[w][mt * 16 + quad * 4];
        #pragma unroll
        for (int nt = 0; nt < 2; ++nt) {
            floatx4 Ca, Cb;
            #pragma unroll
            for (int r = 0; r < 4; ++r) {
                Ca[r] = fmaf(tv[r], w5a[nt], bA0[nt]);
                Cb[r] = fmaf(tv[r], w5b[nt], bB0[nt]);
            }
            Ca = __builtin_amdgcn_mfma_f32_16x16x32_bf16(Af, Ba0f[nt], Ca, 0, 0, 0);
            Cb = __builtin_amdgcn_mfma_f32_16x16x32_bf16(Af, Bb0f[nt], Cb, 0, 0, 0);
            #pragma unroll
            for (int r = 0; r < 4; ++r)
                sA[w][mt * 16 + quad * 4 + r][nt * 16 + n] = (short)f2bf(gate2(Ca[r], Cb[r]));
        }
    }

    // ---- layer 1 ----
    #pragma unroll
    for (int mt = 0; mt < 4; ++mt) {
        const short8 Af = *(const short8*)&sA[w][mt * 16 + n][quad * 8];
        #pragma unroll
        for (int nt = 0; nt < 2; ++nt) {
            floatx4 Ca = { bA1[nt], bA1[nt], bA1[nt], bA1[nt] };
            floatx4 Cb = { bB1[nt], bB1[nt], bB1[nt], bB1[nt] };
            Ca = __builtin_amdgcn_mfma_f32_16x16x32_bf16(Af, Ba1f[nt], Ca, 0, 0, 0);
            Cb = __builtin_amdgcn_mfma_f32_16x16x32_bf16(Af, Bb1f[nt], Cb, 0, 0, 0);
            #pragma unroll
            for (int r = 0; r < 4; ++r)
                sA[w][mt * 16 + quad * 4 + r][nt * 16 + n] = (short)f2bf(gate2(Ca[r], Cb[r]));
        }
    }

    // ---- heads: prefetch all A-frags, then MFMA + fp32 transpose via LDS ----
    short8 Ah[4];
    #pragma unroll
    for (int mt = 0; mt < 4; ++mt)
        Ah[mt] = *(const short8*)&sA[w][mt * 16 + n][quad * 8];
    __syncthreads();   // ordering fence: short-typed reads above vs float stores below

    float* hc = (float*)&sA[w][0][0];   // [tok][12 dwords] fp32, fits in wave zone
    #pragma unroll
    for (int mt = 0; mt < 4; ++mt) {
        floatx4 C = { hbias, hbias, hbias, hbias };
        C = __builtin_amdgcn_mfma_f32_16x16x32_bf16(Ah[mt], Bhf, C, 0, 0, 0);
        if (n < 8) {
            #pragma unroll
            for (int r = 0; r < 4; ++r)
                hc[(mt * 16 + quad * 4 + r) * 12 + n] = C[r];
        }
    }

    const floatx4 h0v = *(const floatx4*)&hc[lane * 12];      // pa, pb, pg, pc0
    const floatx4 h1v = *(const floatx4*)&hc[lane * 12 + 4];  // pc1..pc4

    // ---- per-token epilogue ----
    const float alpha = __expf(h0v[0]);
    const float beta  = __expf(h0v[1]);
    const float gamma = __expf(h0v[2]);
    const float z     = 1.0f - __expf(-(alpha * fabsf(df0) + beta * df1 + gamma * fabsf(df2)));
    const float omz   = 1.0f - z;

    const float c0 = fast_tanh(h0v[3]), c1 = fast_tanh(h1v[0]), c2 = fast_tanh(h1v[1]),
                c3 = fast_tanh(h1v[2]), c4 = fast_tanh(h1v[3]);

    const float hn0 = omz * hp0 + z * c0;
    const float hn1 = omz * hp1 + z * c1;
    const float hn2 = omz * hp2 + z * c2;
    const float hn3 = omz * hp3 + z * c3;
    const float hn4 = omz * hp4 + z * c4;

    float* out_h = out + (size_t)t * 5;
    out_h[0] = hn0; out_h[1] = hn1; out_h[2] = hn2; out_h[3] = hn3; out_h[4] = hn4;
    out[(size_t)N_TOK * 5 + t] =
        hn0 * W_out[0] + hn1 * W_out[1] + hn2 * W_out[2] + hn3 * W_out[3] + hn4 * W_out[4];
}

extern "C" void kernel_launch(void* const* d_in, const int* in_sizes, int n_in,
                              void* d_out, int out_size, void* d_ws, size_t ws_size,
                              hipStream_t stream) {
    const float* h_prev  = (const float*)d_in[0];
    const float* dx      = (const float*)d_in[1];
    const float* Wa0     = (const float*)d_in[2];
    const float* ba0     = (const float*)d_in[3];
    const float* Wb0     = (const float*)d_in[4];
    const float* bb0     = (const float*)d_in[5];
    const float* Wa1     = (const float*)d_in[6];
    const float* ba1     = (const float*)d_in[7];
    const float* Wb1     = (const float*)d_in[8];
    const float* bb1     = (const float*)d_in[9];
    const float* W_alpha = (const float*)d_in[10];
    const float* b_alpha = (const float*)d_in[11];
    const float* W_beta  = (const float*)d_in[12];
    const float* b_beta  = (const float*)d_in[13];
    const float* W_gamma = (const float*)d_in[14];
    const float* b_gamma = (const float*)d_in[15];
    const float* W_c     = (const float*)d_in[16];
    const float* b_c     = (const float*)d_in[17];
    const float* W_out   = (const float*)d_in[18];
    float* out = (float*)d_out;

    chunksum_kernel<<<N_CHUNK, CHUNK, 0, stream>>>(dx);
    msc_kernel<<<N_CHUNK, CHUNK, 0, stream>>>(
        h_prev, dx,
        Wa0, ba0, Wb0, bb0, Wa1, ba1, Wb1, bb1,
        W_alpha, b_alpha, W_beta, b_beta, W_gamma, b_gamma,
        W_c, b_c, W_out, out);
}

// Round 5
// 132.857 us; speedup vs baseline: 1.2122x; 1.2122x over previous
//
#include <hip/hip_runtime.h>

#define B_DIMC   128
#define S_DIMC   4096
#define N_TOK    (B_DIMC * S_DIMC)
#define CHUNK    256                 // tokens per msc block == scan chunk
#define N_CHUNK  (N_TOK / CHUNK)     // 2048
#define CPB      (S_DIMC / CHUNK)    // 16 chunks per batch

typedef __attribute__((ext_vector_type(8))) short  short8;   // 8 bf16 (4 VGPR) MFMA A/B frag
typedef __attribute__((ext_vector_type(4))) float  floatx4;  // MFMA C/D frag
typedef __attribute__((ext_vector_type(4))) int    intx4;

__device__ float g_chunksums[N_CHUNK];

__device__ __forceinline__ unsigned short f2bf(float f) {
    unsigned u = __builtin_bit_cast(unsigned, f);
    u = (u + 0x7FFFu + ((u >> 16) & 1u)) >> 16;   // round-to-nearest-even
    return (unsigned short)u;
}
__device__ __forceinline__ int packbf(float a, float b) {
    return (int)f2bf(a) | ((int)f2bf(b) << 16);
}
// tanh(x) = 1 - 2/(exp2(2*log2e*x)+1); med3 clamp keeps exp2 in range
__device__ __forceinline__ float fast_tanh(float x) {
    float e = __builtin_amdgcn_exp2f(2.885390082f * __builtin_amdgcn_fmed3f(x, -9.0f, 9.0f));
    return fmaf(-2.0f, __builtin_amdgcn_rcpf(e + 1.0f), 1.0f);
}
// tanh(a)*tanh(b) = (t-u)/(t+u),  t = ea*eb+1, u = ea+eb,  e* = exp2(2log2e*x)
__device__ __forceinline__ float gate2(float a, float b) {
    const float c = 2.885390082f;
    float ea = __builtin_amdgcn_exp2f(c * __builtin_amdgcn_fmed3f(a, -9.0f, 9.0f));
    float eb = __builtin_amdgcn_exp2f(c * __builtin_amdgcn_fmed3f(b, -9.0f, 9.0f));
    float t  = fmaf(ea, eb, 1.0f);
    float u  = ea + eb;
    return (t - u) * __builtin_amdgcn_rcpf(t + u);
}

// -------- K1: per-chunk sum of delta_x[..., 2] --------
__global__ __launch_bounds__(256) void chunksum_kernel(const float* __restrict__ dx) {
    const int t    = blockIdx.x * CHUNK + threadIdx.x;
    const int lane = threadIdx.x & 63;
    const int wid  = threadIdx.x >> 6;
    __shared__ float wsum[4];
    float x = dx[(size_t)t * 6 + 2];
    #pragma unroll
    for (int off = 32; off >= 1; off >>= 1) x += __shfl_down(x, off, 64);
    if (lane == 0) wsum[wid] = x;
    __syncthreads();
    if (threadIdx.x == 0)
        g_chunksums[blockIdx.x] = wsum[0] + wsum[1] + wsum[2] + wsum[3];
}

// head weight element for column n, contraction index k
__device__ __forceinline__ float head_w(int n, int k,
                                        const float* Wal, const float* Wbe,
                                        const float* Wga, const float* Wc) {
    if (n == 0) return Wal[k];
    if (n == 1) return Wbe[k];
    if (n == 2) return Wga[k];
    if (n < 8)  return Wc[k * 5 + (n - 3)];
    return 0.0f;
}

// LDS time-multiplex: B-staging area (phase 1) is dead once fragments are in
// registers; A-activation zones (phase 2) reuse the same bytes. Rows padded to
// 40 shorts (80 B, 16B-multiple) to keep b128 frag reads conflict-cheap.
union SMemU {
    struct {
        short W[4][32][40];    // [a0,b0,a1,b1][col n][k] bf16
        short Wh[16][40];      // head [col n][k] bf16
        float Bias[16];
    } b;
    short A[4][64][40];        // per-wave activations [tok][k] bf16 (later fp32 head rows)
};

// -------- K2: MFMA token-parallel MLP with fused scan --------
__global__ __launch_bounds__(256) void msc_kernel(
    const float* __restrict__ h_prev, const float* __restrict__ dx,
    const float* __restrict__ Wa0, const float* __restrict__ ba0,
    const float* __restrict__ Wb0, const float* __restrict__ bb0,
    const float* __restrict__ Wa1, const float* __restrict__ ba1,
    const float* __restrict__ Wb1, const float* __restrict__ bb1,
    const float* __restrict__ W_alpha, const float* __restrict__ b_alpha,
    const float* __restrict__ W_beta,  const float* __restrict__ b_beta,
    const float* __restrict__ W_gamma, const float* __restrict__ b_gamma,
    const float* __restrict__ W_c,     const float* __restrict__ b_c,
    const float* __restrict__ W_out,
    float* __restrict__ out)
{
    __shared__ __align__(16) SMemU sm;
    __shared__ __align__(16) float sTemps[4][64];   // per-wave temp_seq (fp32!)
    __shared__ float sWsum[4];

    const int tid  = threadIdx.x;
    const int w    = tid >> 6;
    const int lane = tid & 63;
    const int n    = lane & 15;
    const int quad = lane >> 4;
    const int t    = blockIdx.x * CHUNK + tid;

    // ---- per-token global loads ----
    const float* hp = h_prev + (size_t)t * 5;
    const float* d  = dx     + (size_t)t * 6;
    const float hp0 = hp[0], hp1 = hp[1], hp2 = hp[2], hp3 = hp[3], hp4 = hp[4];
    const float df0 = d[0], df1 = d[1], df2 = d[2];

    // ---- chunk offset: 1 load/lane + butterfly reduce ----
    const int batch = blockIdx.x / CPB;
    const int cib   = blockIdx.x % CPB;
    float cs = (lane < cib) ? g_chunksums[batch * CPB + lane] : 0.0f;
    #pragma unroll
    for (int m = 1; m < 64; m <<= 1) cs += __shfl_xor(cs, m, 64);
    const float coff = dx[(size_t)batch * S_DIMC * 6 + 5] + cs;   // init_temp + prefix

    // ---- per-lane fp32 epilogue weights (L1/L2-cached) ----
    float w5a[2], w5b[2], bA0[2], bB0[2], bA1[2], bB1[2];
    #pragma unroll
    for (int nt = 0; nt < 2; ++nt) {
        const int col = nt * 16 + n;
        w5a[nt] = Wa0[5 * 32 + col];  w5b[nt] = Wb0[5 * 32 + col];
        bA0[nt] = ba0[col];           bB0[nt] = bb0[col];
        bA1[nt] = ba1[col];           bB1[nt] = bb1[col];
    }

    // ---- wave-level inclusive scan of df2 ----
    float x = df2;
    #pragma unroll
    for (int off = 1; off < 64; off <<= 1) {
        float y = __shfl_up(x, off, 64);
        if (lane >= off) x += y;
    }
    if (lane == 63) sWsum[w] = x;

    // ---- phase 1: cooperative B-operand build (bf16, [col][k], invalid k zeroed) ----
    #pragma unroll
    for (int m = 0; m < 4; ++m) {
        const float* Wsrc = (m == 0) ? Wa0 : (m == 1) ? Wb0 : (m == 2) ? Wa1 : Wb1;
        const bool l0 = (m < 2);
        #pragma unroll
        for (int dd = tid; dd < 512; dd += 256) {
            const int col = dd >> 4, kd = dd & 15, k0 = kd * 2, k1 = k0 + 1;
            float v0, v1;
            if (l0) {
                v0 = (k0 < 9 && k0 != 5) ? Wsrc[k0 * 32 + col] : 0.0f;
                v1 = (k1 < 9 && k1 != 5) ? Wsrc[k1 * 32 + col] : 0.0f;
            } else {
                v0 = Wsrc[k0 * 32 + col];
                v1 = Wsrc[k1 * 32 + col];
            }
            ((int*)&sm.b.W[m][col][0])[kd] = packbf(v0, v1);
        }
    }
    {   // head B: 16 cols x 32 k, one dword per thread
        const int hn = tid >> 4, kd = tid & 15, k0 = kd * 2;
        const float v0 = head_w(hn, k0,     W_alpha, W_beta, W_gamma, W_c);
        const float v1 = head_w(hn, k0 + 1, W_alpha, W_beta, W_gamma, W_c);
        ((int*)&sm.b.Wh[hn][0])[kd] = packbf(v0, v1);
    }
    if (tid < 16) {
        sm.b.Bias[tid] = (tid == 0) ? b_alpha[0] : (tid == 1) ? b_beta[0]
                       : (tid == 2) ? b_gamma[0] : (tid < 8) ? b_c[tid - 3] : 0.0f;
    }

    __syncthreads();   // B staged + sWsum visible

    // ---- B fragments to registers (reused across all 4 M-tiles) ----
    short8 Ba0f[2], Bb0f[2], Ba1f[2], Bb1f[2], Bhf;
    #pragma unroll
    for (int nt = 0; nt < 2; ++nt) {
        const int col = nt * 16 + n;
        Ba0f[nt] = *(const short8*)&sm.b.W[0][col][quad * 8];
        Bb0f[nt] = *(const short8*)&sm.b.W[1][col][quad * 8];
        Ba1f[nt] = *(const short8*)&sm.b.W[2][col][quad * 8];
        Bb1f[nt] = *(const short8*)&sm.b.W[3][col][quad * 8];
    }
    Bhf = *(const short8*)&sm.b.Wh[n][quad * 8];
    const float hbias = sm.b.Bias[n];

    // ---- temp_seq (fp32, stays out of bf16 path) ----
    float pre = coff;
    if (w > 0) pre += sWsum[0];
    if (w > 1) pre += sWsum[1];
    if (w > 2) pre += sWsum[2];
    const float temp_t = pre + x;

    __syncthreads();   // all waves done reading sm.b — safe to overwrite as sm.A

    sTemps[w][lane] = temp_t;

    // ---- phase 2: write layer0 A row: [h(5), 0(temp folded to C), dir(3), 0...] ----
    const float nrm = fmaxf(sqrtf(df0*df0 + df1*df1 + df2*df2), 1e-7f);
    const float inv = __builtin_amdgcn_rcpf(nrm);
    {
        int* arow = (int*)&sm.A[w][lane][0];
        intx4 v0 = { packbf(hp0, hp1), packbf(hp2, hp3),
                     packbf(hp4, 0.0f), packbf(df0*inv, df1*inv) };
        intx4 v1 = { packbf(df2*inv, 0.0f), 0, 0, 0 };
        intx4 z  = { 0, 0, 0, 0 };
        *(intx4*)&arow[0]  = v0;
        *(intx4*)&arow[4]  = v1;
        *(intx4*)&arow[8]  = z;
        *(intx4*)&arow[12] = z;
    }

    // ---- layer 0: C-init = bias + temp*W[5][n] (fp32), MFMA, gate, write G1 ----
    #pragma unroll
    for (int mt = 0; mt < 4; ++mt) {
        const short8  Af = *(const short8*)&sm.A[w][mt * 16 + n][quad * 8];
        const floatx4 tv = *(const floatx4*)&sTemps[w][mt * 16 + quad * 4];
        #pragma unroll
        for (int nt = 0; nt < 2; ++nt) {
            floatx4 Ca, Cb;
            #pragma unroll
            for (int r = 0; r < 4; ++r) {
                Ca[r] = fmaf(tv[r], w5a[nt], bA0[nt]);
                Cb[r] = fmaf(tv[r], w5b[nt], bB0[nt]);
            }
            Ca = __builtin_amdgcn_mfma_f32_16x16x32_bf16(Af, Ba0f[nt], Ca, 0, 0, 0);
            Cb = __builtin_amdgcn_mfma_f32_16x16x32_bf16(Af, Bb0f[nt], Cb, 0, 0, 0);
            #pragma unroll
            for (int r = 0; r < 4; ++r)
                sm.A[w][mt * 16 + quad * 4 + r][nt * 16 + n] = (short)f2bf(gate2(Ca[r], Cb[r]));
        }
    }

    // ---- layer 1 ----
    #pragma unroll
    for (int mt = 0; mt < 4; ++mt) {
        const short8 Af = *(const short8*)&sm.A[w][mt * 16 + n][quad * 8];
        #pragma unroll
        for (int nt = 0; nt < 2; ++nt) {
            floatx4 Ca = { bA1[nt], bA1[nt], bA1[nt], bA1[nt] };
            floatx4 Cb = { bB1[nt], bB1[nt], bB1[nt], bB1[nt] };
            Ca = __builtin_amdgcn_mfma_f32_16x16x32_bf16(Af, Ba1f[nt], Ca, 0, 0, 0);
            Cb = __builtin_amdgcn_mfma_f32_16x16x32_bf16(Af, Bb1f[nt], Cb, 0, 0, 0);
            #pragma unroll
            for (int r = 0; r < 4; ++r)
                sm.A[w][mt * 16 + quad * 4 + r][nt * 16 + n] = (short)f2bf(gate2(Ca[r], Cb[r]));
        }
    }

    // ---- heads: prefetch all A-frags, then MFMA + fp32 transpose via LDS ----
    short8 Ah[4];
    #pragma unroll
    for (int mt = 0; mt < 4; ++mt)
        Ah[mt] = *(const short8*)&sm.A[w][mt * 16 + n][quad * 8];
    __syncthreads();   // ordering fence: short-typed reads above vs float stores below

    float* hc = (float*)&sm.A[w][0][0];   // [tok][12 dwords] fp32, fits in wave zone
    #pragma unroll
    for (int mt = 0; mt < 4; ++mt) {
        floatx4 C = { hbias, hbias, hbias, hbias };
        C = __builtin_amdgcn_mfma_f32_16x16x32_bf16(Ah[mt], Bhf, C, 0, 0, 0);
        if (n < 8) {
            #pragma unroll
            for (int r = 0; r < 4; ++r)
                hc[(mt * 16 + quad * 4 + r) * 12 + n] = C[r];
        }
    }

    const floatx4 h0v = *(const floatx4*)&hc[lane * 12];      // pa, pb, pg, pc0
    const floatx4 h1v = *(const floatx4*)&hc[lane * 12 + 4];  // pc1..pc4

    // ---- per-token epilogue ----
    const float alpha = __expf(h0v[0]);
    const float beta  = __expf(h0v[1]);
    const float gamma = __expf(h0v[2]);
    const float z     = 1.0f - __expf(-(alpha * fabsf(df0) + beta * df1 + gamma * fabsf(df2)));
    const float omz   = 1.0f - z;

    const float c0 = fast_tanh(h0v[3]), c1 = fast_tanh(h1v[0]), c2 = fast_tanh(h1v[1]),
                c3 = fast_tanh(h1v[2]), c4 = fast_tanh(h1v[3]);

    const float hn0 = omz * hp0 + z * c0;
    const float hn1 = omz * hp1 + z * c1;
    const float hn2 = omz * hp2 + z * c2;
    const float hn3 = omz * hp3 + z * c3;
    const float hn4 = omz * hp4 + z * c4;

    float* out_h = out + (size_t)t * 5;
    out_h[0] = hn0; out_h[1] = hn1; out_h[2] = hn2; out_h[3] = hn3; out_h[4] = hn4;
    out[(size_t)N_TOK * 5 + t] =
        hn0 * W_out[0] + hn1 * W_out[1] + hn2 * W_out[2] + hn3 * W_out[3] + hn4 * W_out[4];
}

extern "C" void kernel_launch(void* const* d_in, const int* in_sizes, int n_in,
                              void* d_out, int out_size, void* d_ws, size_t ws_size,
                              hipStream_t stream) {
    const float* h_prev  = (const float*)d_in[0];
    const float* dx      = (const float*)d_in[1];
    const float* Wa0     = (const float*)d_in[2];
    const float* ba0     = (const float*)d_in[3];
    const float* Wb0     = (const float*)d_in[4];
    const float* bb0     = (const float*)d_in[5];
    const float* Wa1     = (const float*)d_in[6];
    const float* ba1     = (const float*)d_in[7];
    const float* Wb1     = (const float*)d_in[8];
    const float* bb1     = (const float*)d_in[9];
    const float* W_alpha = (const float*)d_in[10];
    const float* b_alpha = (const float*)d_in[11];
    const float* W_beta  = (const float*)d_in[12];
    const float* b_beta  = (const float*)d_in[13];
    const float* W_gamma = (const float*)d_in[14];
    const float* b_gamma = (const float*)d_in[15];
    const float* W_c     = (const float*)d_in[16];
    const float* b_c     = (const float*)d_in[17];
    const float* W_out   = (const float*)d_in[18];
    float* out = (float*)d_out;

    chunksum_kernel<<<N_CHUNK, CHUNK, 0, stream>>>(dx);
    msc_kernel<<<N_CHUNK, CHUNK, 0, stream>>>(
        h_prev, dx,
        Wa0, ba0, Wb0, bb0, Wa1, ba1, Wb1, bb1,
        W_alpha, b_alpha, W_beta, b_beta, W_gamma, b_gamma,
        W_c, b_c, W_out, out);
}